// Round 14
// baseline (305.434 us; speedup 1.0000x reference)
//
#include <hip/hip_runtime.h>
#include <hip/hip_bf16.h>
#include <hip/hip_fp16.h>

typedef __attribute__((ext_vector_type(8))) short short8;
typedef __attribute__((ext_vector_type(4))) float floatx4;
typedef _Float16 h2 __attribute__((ext_vector_type(2)));
typedef _Float16 h4 __attribute__((ext_vector_type(4)));
typedef _Float16 h8 __attribute__((ext_vector_type(8)));
typedef __fp16 fp16x2 __attribute__((ext_vector_type(2)));

#define N_NODESC 50000
#define MPAD     50016     // padded to 32-row tiles
#define N_EDGESC 800000
#define E_TOTC   850000    // + self loops
#define IN_DIMC  128
#define FDIM     256       // HEADS*HID
#define HEADSC   4
#define HIDC     64
#define NEG_SLOPE 0.2f
#define RESCALE_THR 8.0f

#define SCAN_TILE 1024
#define SCAN_NB   ((N_NODESC + SCAN_TILE - 1) / SCAN_TILE)   // 49
#define MEAN_NB   400

__device__ __forceinline__ float wave_sum(float v){
  #pragma unroll
  for (int m = 32; m > 0; m >>= 1) v += __shfl_xor(v, m, 64);
  return v;
}
__device__ __forceinline__ int wave_sum_i(int v){
  #pragma unroll
  for (int m = 32; m > 0; m >>= 1) v += __shfl_xor(v, m, 64);
  return v;
}
__device__ __forceinline__ float wave_max(float v){
  #pragma unroll
  for (int m = 32; m > 0; m >>= 1) v = fmaxf(v, __shfl_xor(v, m, 64));
  return v;
}
// 16-lane-group reductions (xor masks stay inside the group)
__device__ __forceinline__ float g16_sum(float v){
  #pragma unroll
  for (int m = 8; m > 0; m >>= 1) v += __shfl_xor(v, m, 64);
  return v;
}
__device__ __forceinline__ float g16_max(float v){
  #pragma unroll
  for (int m = 8; m > 0; m >>= 1) v = fmaxf(v, __shfl_xor(v, m, 64));
  return v;
}

// pack a scalar f32 into both halves of an f16 pair (v_cvt_pkrtz_f16_f32)
__device__ __forceinline__ float f2h2_bits(float v){
  return __builtin_bit_cast(float, __builtin_amdgcn_cvt_pkrtz(v, v));
}
__device__ __forceinline__ float fdot2(h2 a, h2 b, float c){
  return __builtin_amdgcn_fdot2(__builtin_bit_cast(fp16x2, a),
                                __builtin_bit_cast(fp16x2, b), c, false);
}

// ---------- fused prep: blocks 0..399 = edge_attr means; 400..655 = W cvt ----------
__global__ __launch_bounds__(256) void k_prep(const float* __restrict__ ea,
                                              float* __restrict__ meanacc,
                                              const float* __restrict__ W1l,
                                              const float* __restrict__ W1r,
                                              _Float16* __restrict__ Bfrag){
  int b = blockIdx.x;
  if (b < MEAN_NB){
    float s0 = 0.f, s1 = 0.f, s2 = 0.f;
    for (int i = b * 256 + threadIdx.x; i < N_EDGESC; i += MEAN_NB * 256){
      s0 += ea[i*3+0]; s1 += ea[i*3+1]; s2 += ea[i*3+2];
    }
    s0 = wave_sum(s0); s1 = wave_sum(s1); s2 = wave_sum(s2);
    __shared__ float red[3][4];
    int lane = threadIdx.x & 63, w = threadIdx.x >> 6;
    if (lane == 0){ red[0][w] = s0; red[1][w] = s1; red[2][w] = s2; }
    __syncthreads();
    if (threadIdx.x == 0){
      float t0 = 0.f, t1 = 0.f, t2 = 0.f;
      for (int i = 0; i < 4; i++){ t0 += red[0][i]; t1 += red[1][i]; t2 += red[2][i]; }
      atomicAdd(&meanacc[0], t0); atomicAdd(&meanacc[1], t1); atomicAdd(&meanacc[2], t2);
    }
  } else {
    int idx = (b - MEAN_NB) * 256 + threadIdx.x;   // < 65536
    int mat = idx >> 15;
    int r   = idx & 32767;       // k*256+n
    int k   = r >> 8, n = r & 255;
    float v = mat ? W1r[r] : W1l[r];
    int pos = (mat << 15) + (((k >> 3) << 8) + n) * 8 + (k & 7);
    Bfrag[pos] = (_Float16)v;
  }
}

// ---------- degree count + per-edge rank (old counter value) ----------
// rank feeds k_scatter so it needs NO atomics; the RMW return here terminates
// in a store (fire-and-forget, latency hidden). [R12: chain saved ~33 us]
__global__ __launch_bounds__(256) void k_count(const int* __restrict__ ei,
                                               int* __restrict__ deg,
                                               int* __restrict__ rank){
  int e = blockIdx.x * blockDim.x + threadIdx.x;
  if (e >= N_EDGESC) return;
  rank[e] = atomicAdd(&deg[ei[N_EDGESC + e]], 1);
}

// ---------- MFMA dual GEMM (f16): xl = x@W1l, xr = x@W1r ----------
// x loaded directly as f32 + inline cvt (k_cvtx fused away; pad rows zeroed
// by row guard -- reading past x[50000*128] would be OOB).
__global__ __launch_bounds__(256) void k_gemm_mfma(const float* __restrict__ x,
                                                   const _Float16* __restrict__ Bfrag,
                                                   _Float16* __restrict__ xl,
                                                   _Float16* __restrict__ xr){
  const int mat = blockIdx.y;
  const int r0  = blockIdx.x * 32;
  const int w = threadIdx.x >> 6, lane = threadIdx.x & 63;
  const int quad = lane >> 4, l16 = lane & 15;
  const _Float16* Bm = Bfrag + ((size_t)mat << 15);
  _Float16* C = mat ? xr : xl;

  h8 afr[2][4];
  #pragma unroll
  for (int ms = 0; ms < 2; ms++){
    int row = r0 + ms*16 + l16;
    bool ok = row < N_NODESC;
    #pragma unroll
    for (int ks = 0; ks < 4; ks++){
      if (ok){
        const float* p = x + (size_t)row * IN_DIMC + ks*32 + quad*8;
        float4 v0 = *(const float4*)(p);
        float4 v1 = *(const float4*)(p + 4);
        afr[ms][ks] = h8{(_Float16)v0.x, (_Float16)v0.y, (_Float16)v0.z, (_Float16)v0.w,
                         (_Float16)v1.x, (_Float16)v1.y, (_Float16)v1.z, (_Float16)v1.w};
      } else {
        afr[ms][ks] = h8{0,0,0,0,0,0,0,0};
      }
    }
  }
  const int n0 = w * 64;
  floatx4 acc[2][4];
  #pragma unroll
  for (int ms = 0; ms < 2; ms++)
    #pragma unroll
    for (int ns = 0; ns < 4; ns++){
      floatx4 z = {0.f, 0.f, 0.f, 0.f};
      acc[ms][ns] = z;
    }
  #pragma unroll
  for (int ks = 0; ks < 4; ks++){
    #pragma unroll
    for (int ns = 0; ns < 4; ns++){
      int n = n0 + ns*16 + l16;
      int kblk = ks*4 + quad;
      h8 bfr = *reinterpret_cast<const h8*>(Bm + ((size_t)kblk*256 + n)*8);
      acc[0][ns] = __builtin_amdgcn_mfma_f32_16x16x32_f16(afr[0][ks], bfr, acc[0][ns], 0, 0, 0);
      acc[1][ns] = __builtin_amdgcn_mfma_f32_16x16x32_f16(afr[1][ks], bfr, acc[1][ns], 0, 0, 0);
    }
  }
  #pragma unroll
  for (int ms = 0; ms < 2; ms++)
    #pragma unroll
    for (int ns = 0; ns < 4; ns++){
      int col = n0 + ns*16 + l16;
      #pragma unroll
      for (int rg = 0; rg < 4; rg++){
        int row = r0 + ms*16 + quad*4 + rg;
        C[(size_t)row * FDIM + col] = (_Float16)acc[ms][ns][rg];
      }
    }
}

// ---------- 2-phase scan (deg+1 per node: self-loop folded in) ----------
__global__ __launch_bounds__(256) void k_scan_pa(const int* __restrict__ deg,
                                                 int* __restrict__ pre,
                                                 int* __restrict__ bsum){
  int b = blockIdx.x, t = threadIdx.x;
  int lane = t & 63, w = t >> 6;
  int base = b * SCAN_TILE + t * 4;
  int4 v = {0, 0, 0, 0};
  if (base + 3 < N_NODESC){
    v = *(const int4*)(deg + base);
    v.x += 1; v.y += 1; v.z += 1; v.w += 1;      // +1 self-loop each node
  } else {
    if (base + 0 < N_NODESC) v.x = deg[base + 0] + 1;
    if (base + 1 < N_NODESC) v.y = deg[base + 1] + 1;
    if (base + 2 < N_NODESC) v.z = deg[base + 2] + 1;
    if (base + 3 < N_NODESC) v.w = deg[base + 3] + 1;
  }
  int s = v.x + v.y + v.z + v.w;
  int inc = s;
  #pragma unroll
  for (int off = 1; off < 64; off <<= 1){
    int u = __shfl_up(inc, off, 64);
    if (lane >= off) inc += u;
  }
  __shared__ int wsum[4];
  if (lane == 63) wsum[w] = inc;
  __syncthreads();
  int wadd = 0;
  #pragma unroll
  for (int i = 0; i < 4; i++) if (i < w) wadd += wsum[i];
  int excl = inc - s + wadd;
  if (base + 3 < N_NODESC){
    int4 o;
    o.x = excl; o.y = o.x + v.x; o.z = o.y + v.y; o.w = o.z + v.z;
    *(int4*)(pre + base) = o;
  } else {
    int run = excl;
    if (base + 0 < N_NODESC){ pre[base + 0] = run; run += v.x; }
    if (base + 1 < N_NODESC){ pre[base + 1] = run; run += v.y; }
    if (base + 2 < N_NODESC){ pre[base + 2] = run; run += v.z; }
    if (base + 3 < N_NODESC){ pre[base + 3] = run; }
  }
  if (t == 255) bsum[b] = wsum[0] + wsum[1] + wsum[2] + wsum[3];
}

// phase C: each block redundantly reduces the 49 block sums in one wave to
// get its own prefix (k_scan_pb eliminated); block 0 writes the grand total.
__global__ __launch_bounds__(256) void k_scan_pc(const int* __restrict__ pre,
                                                 const int* __restrict__ bsum,
                                                 int* __restrict__ offsets){
  int b = blockIdx.x;
  __shared__ int sadd;
  if (threadIdx.x < 64){
    int lane = threadIdx.x;
    int v   = (lane < SCAN_NB) ? bsum[lane] : 0;
    int pfx = (lane < b) ? v : 0;
    pfx = wave_sum_i(pfx);
    if (lane == 0){
      sadd = pfx;
      if (b == 0){
        // grand total for offsets[N] (sum of all bsum)
      }
    }
    if (b == 0){
      int tot = wave_sum_i(v);
      if (lane == 0) offsets[N_NODESC] = tot;
    }
  }
  __syncthreads();
  int add = sadd;
  int base = b * SCAN_TILE + threadIdx.x * 4;
  if (base + 3 < N_NODESC){
    int4 p = *(const int4*)(pre + base);
    p.x += add; p.y += add; p.z += add; p.w += add;
    *(int4*)(offsets + base) = p;
  } else {
    #pragma unroll
    for (int f = 0; f < 4; f++){
      int i = base + f;
      if (i < N_NODESC) offsets[i] = pre[i] + add;
    }
  }
}

// packed edge record: .x = src (int bits), .y/.z/.w = h2{e,e} pairs (pre-
// converted here while this kernel is memory-bound -- k_attn1 uses them raw).
// position = offsets[dst] + rank[e] (no atomics); self-loop of node i
// deterministically owns slot offsets[i+1]-1 (reserved by +1 in scan).
__global__ __launch_bounds__(256) void k_scatter(const int* __restrict__ ei,
                                                 const float* __restrict__ ea,
                                                 const float* __restrict__ meanacc,
                                                 const int* __restrict__ offsets,
                                                 const int* __restrict__ rank,
                                                 float4* __restrict__ rec){
  int e = blockIdx.x * blockDim.x + threadIdx.x;
  if (e >= E_TOTC) return;
  int pos; float4 r;
  if (e < N_EDGESC){
    int src = ei[e], dst = ei[N_EDGESC + e];
    r.x = __int_as_float(src);
    r.y = f2h2_bits(ea[e*3+0]);
    r.z = f2h2_bits(ea[e*3+1]);
    r.w = f2h2_bits(ea[e*3+2]);
    pos = offsets[dst] + rank[e];
  } else {
    int i = e - N_EDGESC;
    const float inv = 1.0f / (float)N_EDGESC;
    r.x = __int_as_float(i);
    r.y = f2h2_bits(meanacc[0]*inv);
    r.z = f2h2_bits(meanacc[1]*inv);
    r.w = f2h2_bits(meanacc[2]*inv);
    pos = offsets[i + 1] - 1;      // reserved last slot
  }
  rec[pos] = r;
}

// ---------- layer-1 FUSED: one wave per node, 2 edges/iteration ----------
// [R11/R13-verified: 89.5-89.9 us, VALUBusy 83%, VGPR 40. 4-edge regressed
//  (deg/4 too short for the pipeline); (256,8) spills. Edge attrs arrive
//  pre-packed as h2 pairs (R14) -- 3 cvts/iter removed.]
__global__ __launch_bounds__(256, 4) void k_attn1(const int* __restrict__ offsets,
                                                  const float4* __restrict__ rec,
                                                  const _Float16* __restrict__ xl,
                                                  const _Float16* __restrict__ xr,
                                                  const float* __restrict__ W1e,
                                                  const float* __restrict__ att1,
                                                  const float* __restrict__ b1,
                                                  const float* __restrict__ W2l,
                                                  const float* __restrict__ W2r,
                                                  float* __restrict__ sl,
                                                  float* __restrict__ sr){
  const int t = threadIdx.x, lane = t & 63, w = t >> 6;
  const int n = blockIdx.x * 4 + w;
  const int half = lane >> 5, l32 = lane & 31;
  const int f0 = l32 * 8;

  // per-wave invariants: 8 features/lane as f16 pairs
  h2 xrp[4], w0p[4], w1p[4], w2p[4], atp[4];
  {
    h8 xw = *(const h8*)(xr + (size_t)n * FDIM + f0);
    #pragma unroll
    for (int k = 0; k < 4; k++) xrp[k] = h2{xw[2*k], xw[2*k+1]};
    float4 a0 = *(const float4*)(W1e + f0);
    float4 a1 = *(const float4*)(W1e + f0 + 4);
    w0p[0]=h2{(_Float16)a0.x,(_Float16)a0.y}; w0p[1]=h2{(_Float16)a0.z,(_Float16)a0.w};
    w0p[2]=h2{(_Float16)a1.x,(_Float16)a1.y}; w0p[3]=h2{(_Float16)a1.z,(_Float16)a1.w};
    float4 b0 = *(const float4*)(W1e + FDIM + f0);
    float4 b4 = *(const float4*)(W1e + FDIM + f0 + 4);
    w1p[0]=h2{(_Float16)b0.x,(_Float16)b0.y}; w1p[1]=h2{(_Float16)b0.z,(_Float16)b0.w};
    w1p[2]=h2{(_Float16)b4.x,(_Float16)b4.y}; w1p[3]=h2{(_Float16)b4.z,(_Float16)b4.w};
    float4 c0 = *(const float4*)(W1e + 2*FDIM + f0);
    float4 c4 = *(const float4*)(W1e + 2*FDIM + f0 + 4);
    w2p[0]=h2{(_Float16)c0.x,(_Float16)c0.y}; w2p[1]=h2{(_Float16)c0.z,(_Float16)c0.w};
    w2p[2]=h2{(_Float16)c4.x,(_Float16)c4.y}; w2p[3]=h2{(_Float16)c4.z,(_Float16)c4.w};
    float4 d0 = *(const float4*)(att1 + f0);
    float4 d4 = *(const float4*)(att1 + f0 + 4);
    atp[0]=h2{(_Float16)d0.x,(_Float16)d0.y}; atp[1]=h2{(_Float16)d0.z,(_Float16)d0.w};
    atp[2]=h2{(_Float16)d4.x,(_Float16)d4.y}; atp[3]=h2{(_Float16)d4.z,(_Float16)d4.w};
  }
  const h2 nsl2 = h2{(_Float16)NEG_SLOPE, (_Float16)NEG_SLOPE};
  const int beg = offsets[n], end = offsets[n + 1];
  const int last = end - 1;

  float m = -1e30f, den = 0.f;
  float acc[8] = {0.f,0.f,0.f,0.f,0.f,0.f,0.f,0.f};

  // pipeline prologue (this half's edge stream: beg+half, step 2)
  int j = beg + half;
  float4 rc  = rec[min(j, last)];
  float4 rcn = rec[min(j + 2, last)];
  unsigned off0 = ((unsigned)__float_as_int(rc.x) << 8) + f0;  // elements, fits 32b
  h8 raw = *(const h8*)(xl + off0);

  for (; j < end; j += 2){
    // issue next gather + record 2 ahead
    unsigned offn = ((unsigned)__float_as_int(rcn.x) << 8) + f0;
    h8 rawn = *(const h8*)(xl + offn);
    h2 he0 = __builtin_bit_cast(h2, rc.y);
    h2 he1 = __builtin_bit_cast(h2, rc.z);
    h2 he2 = __builtin_bit_cast(h2, rc.w);
    rc = rcn;
    rcn = rec[min(j + 4, last)];

    float pp = 0.f;
    #pragma unroll
    for (int k = 0; k < 4; k++){
      h2 xk = h2{raw[2*k], raw[2*k+1]};
      h2 v = xk + xrp[k] + he0*w0p[k] + he1*w1p[k] + he2*w2p[k];
      v = __builtin_elementwise_max(v, nsl2 * v);
      pp = fdot2(v, atp[k], pp);
    }
    // 8-lane (per-head, per-half) reduce
    pp += __shfl_xor(pp, 1, 64);
    pp += __shfl_xor(pp, 2, 64);
    pp += __shfl_xor(pp, 4, 64);

    // deferred-max online softmax (per half)
    if (pp > m + RESCALE_THR){
      float corr = __expf(m - pp);
      den *= corr;
      #pragma unroll
      for (int k = 0; k < 8; k++) acc[k] *= corr;
      m = pp;
    }
    float al = __expf(pp - m);
    den += al;
    #pragma unroll
    for (int k = 0; k < 8; k++) acc[k] = fmaf((float)raw[k], al, acc[k]);

    raw = rawn;
  }

  // exact merge of the two halves' softmax states
  float m_o   = __shfl_xor(m, 32, 64);
  float den_o = __shfl_xor(den, 32, 64);
  float m_t = fmaxf(m, m_o);
  float sc   = __expf(m - m_t);
  float sc_o = __expf(m_o - m_t);
  float den_t = den * sc + den_o * sc_o;
  float invd = 1.0f / den_t;

  float4 bb0 = *(const float4*)(b1 + f0);
  float4 bb4 = *(const float4*)(b1 + f0 + 4);
  float bb[8] = {bb0.x,bb0.y,bb0.z,bb0.w,bb4.x,bb4.y,bb4.z,bb4.w};
  float hv[8];
  #pragma unroll
  for (int k = 0; k < 8; k++){
    float a_o = __shfl_xor(acc[k], 32, 64);
    float tot = acc[k] * sc + a_o * sc_o;
    float h = tot * invd + bb[k];
    hv[k] = (h > 0.f) ? h : (__expf(h) - 1.f);   // ELU
  }
  float4 l0 = *(const float4*)(W2l + f0);
  float4 l4 = *(const float4*)(W2l + f0 + 4);
  float4 r0 = *(const float4*)(W2r + f0);
  float4 r4 = *(const float4*)(W2r + f0 + 4);
  float wl[8] = {l0.x,l0.y,l0.z,l0.w,l4.x,l4.y,l4.z,l4.w};
  float wr[8] = {r0.x,r0.y,r0.z,r0.w,r4.x,r4.y,r4.z,r4.w};
  float pa = 0.f, pb = 0.f;
  #pragma unroll
  for (int k = 0; k < 8; k++){ pa += hv[k]*wl[k]; pb += hv[k]*wr[k]; }
  // reduce over 32 lanes (halves hold identical values post-merge)
  #pragma unroll
  for (int msk = 16; msk > 0; msk >>= 1){
    pa += __shfl_xor(pa, msk, 64);
    pb += __shfl_xor(pb, msk, 64);
  }
  if (lane == 0){ sl[n] = pa; sr[n] = pb; }
}

// ---------- global softmax key helpers ----------
__device__ __forceinline__ unsigned fkey(float f){
  unsigned u = __float_as_uint(f);
  return u ^ ((u >> 31) ? 0xFFFFFFFFu : 0x80000000u);
}
__device__ __forceinline__ float funkey(unsigned k){
  unsigned u = (k >> 31) ? (k ^ 0x80000000u) : ~k;
  return __uint_as_float(u);
}

// ---------- layer-2 FUSED: 16-lane group per node (16 nodes/block) ----------
__global__ __launch_bounds__(256) void k_attn2(const int* __restrict__ offsets,
                                               const float4* __restrict__ rec,
                                               const float* __restrict__ W2e,
                                               const float* __restrict__ att2,
                                               const float* __restrict__ b2p,
                                               const float* __restrict__ sl,
                                               const float* __restrict__ sr,
                                               float* __restrict__ scores,
                                               float* __restrict__ out){
  int t = threadIdx.x, l16 = t & 15;
  int n = blockIdx.x * 16 + (t >> 4);
  if (n >= N_NODESC) return;
  const float attv = att2[0];
  const float w2e0 = W2e[0], w2e1 = W2e[1], w2e2 = W2e[2];
  const float srn = sr[n];
  int beg = offsets[n], end = offsets[n + 1];
  float m = -1e30f, den = 0.f, num = 0.f;
  for (int j = beg + l16; j < end; j += 16){
    float4 rc = rec[j];
    float slv = sl[__float_as_int(rc.x)];
    float e0 = (float)__builtin_bit_cast(h2, rc.y)[0];
    float e1 = (float)__builtin_bit_cast(h2, rc.z)[0];
    float e2 = (float)__builtin_bit_cast(h2, rc.w)[0];
    float v = slv + srn + e0*w2e0 + e1*w2e1 + e2*w2e2;
    v = (v > 0.f) ? v : NEG_SLOPE * v;
    float lg = v * attv;
    float mn = fmaxf(m, lg);
    float corr = __expf(m - mn);
    float pe   = __expf(lg - mn);
    den = den * corr + pe;
    num = num * corr + pe * slv;
    m = mn;
  }
  float mg = g16_max(m);
  float scale = __expf(m - mg);
  float deng = g16_sum(den * scale);
  float numg = g16_sum(num * scale);
  if (l16 == 0){
    float s = numg / deng + b2p[0];
    scores[n] = s;
    out[N_NODESC + n] = s;
  }
}

// ---------- global softmax over scores (block-reduce then 1 atomic/block) ----------
__global__ __launch_bounds__(256) void k_smax_max(const float* __restrict__ scores,
                                                  unsigned* __restrict__ redmax){
  float m = -1e30f;
  for (int i = blockIdx.x * blockDim.x + threadIdx.x; i < N_NODESC;
       i += gridDim.x * blockDim.x)
    m = fmaxf(m, scores[i]);
  m = wave_max(m);
  __shared__ float ws_[4];
  int lane = threadIdx.x & 63, w = threadIdx.x >> 6;
  if (lane == 0) ws_[w] = m;
  __syncthreads();
  if (threadIdx.x == 0){
    for (int i = 1; i < 4; i++) m = fmaxf(m, ws_[i]);
    atomicMax(redmax, fkey(m));
  }
}

__global__ __launch_bounds__(256) void k_smax_sum(const float* __restrict__ scores,
                                                  const unsigned* __restrict__ redmax,
                                                  float* __restrict__ redsum){
  float mx = funkey(*redmax);
  float s = 0.f;
  for (int i = blockIdx.x * blockDim.x + threadIdx.x; i < N_NODESC;
       i += gridDim.x * blockDim.x)
    s += __expf(scores[i] - mx);
  s = wave_sum(s);
  __shared__ float ws_[4];
  int lane = threadIdx.x & 63, w = threadIdx.x >> 6;
  if (lane == 0) ws_[w] = s;
  __syncthreads();
  if (threadIdx.x == 0){
    float t = 0.f;
    for (int i = 0; i < 4; i++) t += ws_[i];
    atomicAdd(redsum, t);
  }
}

__global__ __launch_bounds__(256) void k_smax_write(const float* __restrict__ scores,
                                                    const unsigned* __restrict__ redmax,
                                                    const float* __restrict__ redsum,
                                                    float* __restrict__ out){
  int i = blockIdx.x * blockDim.x + threadIdx.x;
  if (i >= N_NODESC) return;
  float mx = funkey(*redmax);
  float inv = 1.0f / (*redsum);
  out[i] = __expf(scores[i] - mx) * inv;
}

extern "C" void kernel_launch(void* const* d_in, const int* in_sizes, int n_in,
                              void* d_out, int out_size, void* d_ws, size_t ws_size,
                              hipStream_t stream) {
  const float* x    = (const float*)d_in[0];
  const float* ea   = (const float*)d_in[1];
  const float* W1l  = (const float*)d_in[2];
  const float* W1r  = (const float*)d_in[3];
  const float* W1e  = (const float*)d_in[4];
  const float* att1 = (const float*)d_in[5];
  const float* b1   = (const float*)d_in[6];
  const float* W2l  = (const float*)d_in[7];
  const float* W2r  = (const float*)d_in[8];
  const float* W2e  = (const float*)d_in[9];
  const float* att2 = (const float*)d_in[10];
  const float* b2   = (const float*)d_in[11];
  const int*   ei   = (const int*)d_in[12];
  float* out = (float*)d_out;

  char* w = (char*)d_ws;
  size_t off = 0;
  auto alloc = [&](size_t bytes) -> char* {
    char* p = w + off;
    off = (off + bytes + 255) & ~(size_t)255;
    return p;
  };
  // ---- zero zone (memset every call) ----
  float*    meanacc = (float*)alloc(16);
  unsigned* redmax  = (unsigned*)alloc(8);
  float*    redsum  = (float*)((char*)redmax + 4);
  int*      deg     = (int*)alloc((size_t)N_NODESC * 4);
  size_t zero_bytes = off;
  // ---- rest ----
  int*   offsets = (int*)alloc((size_t)(N_NODESC + 1) * 4);
  int*   rank    = (int*)alloc((size_t)N_EDGESC * 4);
  int*   pre     = (int*)alloc((size_t)N_NODESC * 4);
  int*   bsum    = (int*)alloc((size_t)SCAN_NB * 4);
  float4* rec    = (float4*)alloc((size_t)E_TOTC * 16);
  float* sl      = (float*)alloc((size_t)N_NODESC * 4);
  float* sr      = (float*)alloc((size_t)N_NODESC * 4);
  float* scores  = (float*)alloc((size_t)N_NODESC * 4);
  _Float16* Bfrag = (_Float16*)alloc((size_t)2 * 128 * 256 * 2);
  _Float16* xl    = (_Float16*)alloc((size_t)MPAD * FDIM * 2);
  _Float16* xr    = (_Float16*)alloc((size_t)MPAD * FDIM * 2);
  (void)ws_size; (void)in_sizes; (void)n_in; (void)out_size;

  hipMemsetAsync(d_ws, 0, zero_bytes, stream);

  k_prep  <<<MEAN_NB + 256, 256, 0, stream>>>(ea, meanacc, W1l, W1r, Bfrag);
  k_count <<<(N_EDGESC + 255) / 256, 256, 0, stream>>>(ei, deg, rank);
  k_scan_pa<<<SCAN_NB, 256, 0, stream>>>(deg, pre, bsum);
  k_scan_pc<<<SCAN_NB, 256, 0, stream>>>(pre, bsum, offsets);
  k_scatter<<<(E_TOTC + 255) / 256, 256, 0, stream>>>(ei, ea, meanacc, offsets,
                                                      rank, rec);
  {
    dim3 g(MPAD / 32, 2);
    k_gemm_mfma<<<g, 256, 0, stream>>>(x, Bfrag, xl, xr);
  }
  k_attn1 <<<N_NODESC / 4, 256, 0, stream>>>(offsets, rec, xl, xr,
                                             W1e, att1, b1, W2l, W2r, sl, sr);
  k_attn2 <<<(N_NODESC + 15) / 16, 256, 0, stream>>>(offsets, rec, W2e, att2, b2,
                                                     sl, sr, scores, out);
  k_smax_max <<<256, 256, 0, stream>>>(scores, redmax);
  k_smax_sum <<<256, 256, 0, stream>>>(scores, redmax, redsum);
  k_smax_write<<<(N_NODESC + 255) / 256, 256, 0, stream>>>(scores, redmax, redsum, out);
}

// Round 15
// 304.219 us; speedup vs baseline: 1.0040x; 1.0040x over previous
//
#include <hip/hip_runtime.h>
#include <hip/hip_bf16.h>
#include <hip/hip_fp16.h>

typedef __attribute__((ext_vector_type(8))) short short8;
typedef __attribute__((ext_vector_type(4))) float floatx4;
typedef _Float16 h2 __attribute__((ext_vector_type(2)));
typedef _Float16 h4 __attribute__((ext_vector_type(4)));
typedef _Float16 h8 __attribute__((ext_vector_type(8)));
typedef __fp16 fp16x2 __attribute__((ext_vector_type(2)));

#define N_NODESC 50000
#define MPAD     50016     // padded to 32-row tiles
#define N_EDGESC 800000
#define E_TOTC   850000    // + self loops
#define IN_DIMC  128
#define FDIM     256       // HEADS*HID
#define HEADSC   4
#define HIDC     64
#define NEG_SLOPE 0.2f
#define RESCALE_THR 8.0f

#define SCAN_TILE 1024
#define SCAN_NB   ((N_NODESC + SCAN_TILE - 1) / SCAN_TILE)   // 49
#define MEAN_NB   400

__device__ __forceinline__ float wave_sum(float v){
  #pragma unroll
  for (int m = 32; m > 0; m >>= 1) v += __shfl_xor(v, m, 64);
  return v;
}
__device__ __forceinline__ int wave_sum_i(int v){
  #pragma unroll
  for (int m = 32; m > 0; m >>= 1) v += __shfl_xor(v, m, 64);
  return v;
}
__device__ __forceinline__ float wave_max(float v){
  #pragma unroll
  for (int m = 32; m > 0; m >>= 1) v = fmaxf(v, __shfl_xor(v, m, 64));
  return v;
}
// 16-lane-group reductions (xor masks stay inside the group)
__device__ __forceinline__ float g16_sum(float v){
  #pragma unroll
  for (int m = 8; m > 0; m >>= 1) v += __shfl_xor(v, m, 64);
  return v;
}
__device__ __forceinline__ float g16_max(float v){
  #pragma unroll
  for (int m = 8; m > 0; m >>= 1) v = fmaxf(v, __shfl_xor(v, m, 64));
  return v;
}

// pack a scalar f32 into both halves of an f16 pair (v_cvt_pkrtz_f16_f32)
__device__ __forceinline__ h2 f2h2(float v){
  return __builtin_bit_cast(h2, __builtin_amdgcn_cvt_pkrtz(v, v));
}
__device__ __forceinline__ float fdot2(h2 a, h2 b, float c){
  return __builtin_amdgcn_fdot2(__builtin_bit_cast(fp16x2, a),
                                __builtin_bit_cast(fp16x2, b), c, false);
}

// ---------- fused prep: blocks 0..399 = edge_attr means; 400..655 = W cvt ----------
__global__ __launch_bounds__(256) void k_prep(const float* __restrict__ ea,
                                              float* __restrict__ meanacc,
                                              const float* __restrict__ W1l,
                                              const float* __restrict__ W1r,
                                              _Float16* __restrict__ Bfrag){
  int b = blockIdx.x;
  if (b < MEAN_NB){
    float s0 = 0.f, s1 = 0.f, s2 = 0.f;
    for (int i = b * 256 + threadIdx.x; i < N_EDGESC; i += MEAN_NB * 256){
      s0 += ea[i*3+0]; s1 += ea[i*3+1]; s2 += ea[i*3+2];
    }
    s0 = wave_sum(s0); s1 = wave_sum(s1); s2 = wave_sum(s2);
    __shared__ float red[3][4];
    int lane = threadIdx.x & 63, w = threadIdx.x >> 6;
    if (lane == 0){ red[0][w] = s0; red[1][w] = s1; red[2][w] = s2; }
    __syncthreads();
    if (threadIdx.x == 0){
      float t0 = 0.f, t1 = 0.f, t2 = 0.f;
      for (int i = 0; i < 4; i++){ t0 += red[0][i]; t1 += red[1][i]; t2 += red[2][i]; }
      atomicAdd(&meanacc[0], t0); atomicAdd(&meanacc[1], t1); atomicAdd(&meanacc[2], t2);
    }
  } else {
    int idx = (b - MEAN_NB) * 256 + threadIdx.x;   // < 65536
    int mat = idx >> 15;
    int r   = idx & 32767;       // k*256+n
    int k   = r >> 8, n = r & 255;
    float v = mat ? W1r[r] : W1l[r];
    int pos = (mat << 15) + (((k >> 3) << 8) + n) * 8 + (k & 7);
    Bfrag[pos] = (_Float16)v;
  }
}

// ---------- degree count + per-edge rank (old counter value) ----------
// rank feeds k_scatter so it needs NO atomics; the RMW return here terminates
// in a store (fire-and-forget, latency hidden). [R12: chain saved ~33 us]
__global__ __launch_bounds__(256) void k_count(const int* __restrict__ ei,
                                               int* __restrict__ deg,
                                               int* __restrict__ rank){
  int e = blockIdx.x * blockDim.x + threadIdx.x;
  if (e >= N_EDGESC) return;
  rank[e] = atomicAdd(&deg[ei[N_EDGESC + e]], 1);
}

// ---------- MFMA dual GEMM (f16): xl = x@W1l, xr = x@W1r ----------
// Single pass: one block loads its 32 x-rows ONCE (f32 + inline cvt; k_cvtx
// fused away) and computes BOTH output mats sequentially (R15: halves x reads).
__global__ __launch_bounds__(256) void k_gemm_mfma(const float* __restrict__ x,
                                                   const _Float16* __restrict__ Bfrag,
                                                   _Float16* __restrict__ xl,
                                                   _Float16* __restrict__ xr){
  const int r0  = blockIdx.x * 32;
  const int w = threadIdx.x >> 6, lane = threadIdx.x & 63;
  const int quad = lane >> 4, l16 = lane & 15;

  h8 afr[2][4];
  #pragma unroll
  for (int ms = 0; ms < 2; ms++){
    int row = r0 + ms*16 + l16;
    bool ok = row < N_NODESC;
    #pragma unroll
    for (int ks = 0; ks < 4; ks++){
      if (ok){
        const float* p = x + (size_t)row * IN_DIMC + ks*32 + quad*8;
        float4 v0 = *(const float4*)(p);
        float4 v1 = *(const float4*)(p + 4);
        afr[ms][ks] = h8{(_Float16)v0.x, (_Float16)v0.y, (_Float16)v0.z, (_Float16)v0.w,
                         (_Float16)v1.x, (_Float16)v1.y, (_Float16)v1.z, (_Float16)v1.w};
      } else {
        afr[ms][ks] = h8{0,0,0,0,0,0,0,0};
      }
    }
  }
  const int n0 = w * 64;
  #pragma unroll
  for (int mat = 0; mat < 2; mat++){
    const _Float16* Bm = Bfrag + ((size_t)mat << 15);
    _Float16* C = mat ? xr : xl;
    floatx4 acc[2][4];
    #pragma unroll
    for (int ms = 0; ms < 2; ms++)
      #pragma unroll
      for (int ns = 0; ns < 4; ns++){
        floatx4 z = {0.f, 0.f, 0.f, 0.f};
        acc[ms][ns] = z;
      }
    #pragma unroll
    for (int ks = 0; ks < 4; ks++){
      #pragma unroll
      for (int ns = 0; ns < 4; ns++){
        int n = n0 + ns*16 + l16;
        int kblk = ks*4 + quad;
        h8 bfr = *reinterpret_cast<const h8*>(Bm + ((size_t)kblk*256 + n)*8);
        acc[0][ns] = __builtin_amdgcn_mfma_f32_16x16x32_f16(afr[0][ks], bfr, acc[0][ns], 0, 0, 0);
        acc[1][ns] = __builtin_amdgcn_mfma_f32_16x16x32_f16(afr[1][ks], bfr, acc[1][ns], 0, 0, 0);
      }
    }
    #pragma unroll
    for (int ms = 0; ms < 2; ms++)
      #pragma unroll
      for (int ns = 0; ns < 4; ns++){
        int col = n0 + ns*16 + l16;
        #pragma unroll
        for (int rg = 0; rg < 4; rg++){
          int row = r0 + ms*16 + quad*4 + rg;
          C[(size_t)row * FDIM + col] = (_Float16)acc[ms][ns][rg];
        }
      }
  }
}

// ---------- 2-phase scan (deg+1 per node: self-loop folded in) ----------
__global__ __launch_bounds__(256) void k_scan_pa(const int* __restrict__ deg,
                                                 int* __restrict__ pre,
                                                 int* __restrict__ bsum){
  int b = blockIdx.x, t = threadIdx.x;
  int lane = t & 63, w = t >> 6;
  int base = b * SCAN_TILE + t * 4;
  int4 v = {0, 0, 0, 0};
  if (base + 3 < N_NODESC){
    v = *(const int4*)(deg + base);
    v.x += 1; v.y += 1; v.z += 1; v.w += 1;      // +1 self-loop each node
  } else {
    if (base + 0 < N_NODESC) v.x = deg[base + 0] + 1;
    if (base + 1 < N_NODESC) v.y = deg[base + 1] + 1;
    if (base + 2 < N_NODESC) v.z = deg[base + 2] + 1;
    if (base + 3 < N_NODESC) v.w = deg[base + 3] + 1;
  }
  int s = v.x + v.y + v.z + v.w;
  int inc = s;
  #pragma unroll
  for (int off = 1; off < 64; off <<= 1){
    int u = __shfl_up(inc, off, 64);
    if (lane >= off) inc += u;
  }
  __shared__ int wsum[4];
  if (lane == 63) wsum[w] = inc;
  __syncthreads();
  int wadd = 0;
  #pragma unroll
  for (int i = 0; i < 4; i++) if (i < w) wadd += wsum[i];
  int excl = inc - s + wadd;
  if (base + 3 < N_NODESC){
    int4 o;
    o.x = excl; o.y = o.x + v.x; o.z = o.y + v.y; o.w = o.z + v.z;
    *(int4*)(pre + base) = o;
  } else {
    int run = excl;
    if (base + 0 < N_NODESC){ pre[base + 0] = run; run += v.x; }
    if (base + 1 < N_NODESC){ pre[base + 1] = run; run += v.y; }
    if (base + 2 < N_NODESC){ pre[base + 2] = run; run += v.z; }
    if (base + 3 < N_NODESC){ pre[base + 3] = run; }
  }
  if (t == 255) bsum[b] = wsum[0] + wsum[1] + wsum[2] + wsum[3];
}

// phase C: each block redundantly reduces the 49 block sums in one wave to
// get its own prefix (k_scan_pb eliminated); block 0 writes the grand total.
__global__ __launch_bounds__(256) void k_scan_pc(const int* __restrict__ pre,
                                                 const int* __restrict__ bsum,
                                                 int* __restrict__ offsets){
  int b = blockIdx.x;
  __shared__ int sadd;
  if (threadIdx.x < 64){
    int lane = threadIdx.x;
    int v   = (lane < SCAN_NB) ? bsum[lane] : 0;
    int pfx = (lane < b) ? v : 0;
    pfx = wave_sum_i(pfx);
    if (lane == 0) sadd = pfx;
    if (b == 0){
      int tot = wave_sum_i(v);
      if (lane == 0) offsets[N_NODESC] = tot;
    }
  }
  __syncthreads();
  int add = sadd;
  int base = b * SCAN_TILE + threadIdx.x * 4;
  if (base + 3 < N_NODESC){
    int4 p = *(const int4*)(pre + base);
    p.x += add; p.y += add; p.z += add; p.w += add;
    *(int4*)(offsets + base) = p;
  } else {
    #pragma unroll
    for (int f = 0; f < 4; f++){
      int i = base + f;
      if (i < N_NODESC) offsets[i] = pre[i] + add;
    }
  }
}

// packed edge record: .x = src (int bits), .y/.z/.w = edge_attr (f32 --
// R14's h2-prepack regressed attn1 92.0 vs 89.5, reverted).
// position = offsets[dst] + rank[e] (no atomics); self-loop of node i
// deterministically owns slot offsets[i+1]-1 (reserved by +1 in scan).
__global__ __launch_bounds__(256) void k_scatter(const int* __restrict__ ei,
                                                 const float* __restrict__ ea,
                                                 const float* __restrict__ meanacc,
                                                 const int* __restrict__ offsets,
                                                 const int* __restrict__ rank,
                                                 float4* __restrict__ rec){
  int e = blockIdx.x * blockDim.x + threadIdx.x;
  if (e >= E_TOTC) return;
  int pos; float4 r;
  if (e < N_EDGESC){
    int src = ei[e], dst = ei[N_EDGESC + e];
    r.x = __int_as_float(src);
    r.y = ea[e*3+0]; r.z = ea[e*3+1]; r.w = ea[e*3+2];
    pos = offsets[dst] + rank[e];
  } else {
    int i = e - N_EDGESC;
    const float inv = 1.0f / (float)N_EDGESC;
    r.x = __int_as_float(i);
    r.y = meanacc[0]*inv; r.z = meanacc[1]*inv; r.w = meanacc[2]*inv;
    pos = offsets[i + 1] - 1;      // reserved last slot
  }
  rec[pos] = r;
}

// ---------- layer-1 FUSED: one wave per node, 2 edges/iteration ----------
// [R11/R13-verified: 89.5-89.9 us, VALUBusy 83%, VGPR 40. 4-edge regressed
//  (deg/4 too short for the pipeline); (256,8) spills; h2-prepack regressed.]
// 32-lane half-wave owns one edge; lane owns 8 features (f0 = (lane&31)*8,
// head = (lane&31)>>3). Each half runs an independent deferred-max online
// softmax over its even/odd edge subsequence; exact merge via shfl_xor(32).
__global__ __launch_bounds__(256, 4) void k_attn1(const int* __restrict__ offsets,
                                                  const float4* __restrict__ rec,
                                                  const _Float16* __restrict__ xl,
                                                  const _Float16* __restrict__ xr,
                                                  const float* __restrict__ W1e,
                                                  const float* __restrict__ att1,
                                                  const float* __restrict__ b1,
                                                  const float* __restrict__ W2l,
                                                  const float* __restrict__ W2r,
                                                  float* __restrict__ sl,
                                                  float* __restrict__ sr){
  const int t = threadIdx.x, lane = t & 63, w = t >> 6;
  const int n = blockIdx.x * 4 + w;
  const int half = lane >> 5, l32 = lane & 31;
  const int f0 = l32 * 8;

  // per-wave invariants: 8 features/lane as f16 pairs
  h2 xrp[4], w0p[4], w1p[4], w2p[4], atp[4];
  {
    h8 xw = *(const h8*)(xr + (size_t)n * FDIM + f0);
    #pragma unroll
    for (int k = 0; k < 4; k++) xrp[k] = h2{xw[2*k], xw[2*k+1]};
    float4 a0 = *(const float4*)(W1e + f0);
    float4 a1 = *(const float4*)(W1e + f0 + 4);
    w0p[0]=h2{(_Float16)a0.x,(_Float16)a0.y}; w0p[1]=h2{(_Float16)a0.z,(_Float16)a0.w};
    w0p[2]=h2{(_Float16)a1.x,(_Float16)a1.y}; w0p[3]=h2{(_Float16)a1.z,(_Float16)a1.w};
    float4 b0 = *(const float4*)(W1e + FDIM + f0);
    float4 b4 = *(const float4*)(W1e + FDIM + f0 + 4);
    w1p[0]=h2{(_Float16)b0.x,(_Float16)b0.y}; w1p[1]=h2{(_Float16)b0.z,(_Float16)b0.w};
    w1p[2]=h2{(_Float16)b4.x,(_Float16)b4.y}; w1p[3]=h2{(_Float16)b4.z,(_Float16)b4.w};
    float4 c0 = *(const float4*)(W1e + 2*FDIM + f0);
    float4 c4 = *(const float4*)(W1e + 2*FDIM + f0 + 4);
    w2p[0]=h2{(_Float16)c0.x,(_Float16)c0.y}; w2p[1]=h2{(_Float16)c0.z,(_Float16)c0.w};
    w2p[2]=h2{(_Float16)c4.x,(_Float16)c4.y}; w2p[3]=h2{(_Float16)c4.z,(_Float16)c4.w};
    float4 d0 = *(const float4*)(att1 + f0);
    float4 d4 = *(const float4*)(att1 + f0 + 4);
    atp[0]=h2{(_Float16)d0.x,(_Float16)d0.y}; atp[1]=h2{(_Float16)d0.z,(_Float16)d0.w};
    atp[2]=h2{(_Float16)d4.x,(_Float16)d4.y}; atp[3]=h2{(_Float16)d4.z,(_Float16)d4.w};
  }
  const h2 nsl2 = h2{(_Float16)NEG_SLOPE, (_Float16)NEG_SLOPE};
  const int beg = offsets[n], end = offsets[n + 1];
  const int last = end - 1;

  float m = -1e30f, den = 0.f;
  float acc[8] = {0.f,0.f,0.f,0.f,0.f,0.f,0.f,0.f};

  // pipeline prologue (this half's edge stream: beg+half, step 2)
  int j = beg + half;
  float4 rc  = rec[min(j, last)];
  float4 rcn = rec[min(j + 2, last)];
  unsigned off0 = ((unsigned)__float_as_int(rc.x) << 8) + f0;  // elements, fits 32b
  h8 raw = *(const h8*)(xl + off0);

  for (; j < end; j += 2){
    // issue next gather + record 2 ahead
    unsigned offn = ((unsigned)__float_as_int(rcn.x) << 8) + f0;
    h8 rawn = *(const h8*)(xl + offn);
    const float e0 = rc.y, e1 = rc.z, e2 = rc.w;
    rc = rcn;
    rcn = rec[min(j + 4, last)];

    h2 he0 = f2h2(e0), he1 = f2h2(e1), he2 = f2h2(e2);
    float pp = 0.f;
    #pragma unroll
    for (int k = 0; k < 4; k++){
      h2 xk = h2{raw[2*k], raw[2*k+1]};
      h2 v = xk + xrp[k] + he0*w0p[k] + he1*w1p[k] + he2*w2p[k];
      v = __builtin_elementwise_max(v, nsl2 * v);
      pp = fdot2(v, atp[k], pp);
    }
    // 8-lane (per-head, per-half) reduce
    pp += __shfl_xor(pp, 1, 64);
    pp += __shfl_xor(pp, 2, 64);
    pp += __shfl_xor(pp, 4, 64);

    // deferred-max online softmax (per half)
    if (pp > m + RESCALE_THR){
      float corr = __expf(m - pp);
      den *= corr;
      #pragma unroll
      for (int k = 0; k < 8; k++) acc[k] *= corr;
      m = pp;
    }
    float al = __expf(pp - m);
    den += al;
    #pragma unroll
    for (int k = 0; k < 8; k++) acc[k] = fmaf((float)raw[k], al, acc[k]);

    raw = rawn;
  }

  // exact merge of the two halves' softmax states
  float m_o   = __shfl_xor(m, 32, 64);
  float den_o = __shfl_xor(den, 32, 64);
  float m_t = fmaxf(m, m_o);
  float sc   = __expf(m - m_t);
  float sc_o = __expf(m_o - m_t);
  float den_t = den * sc + den_o * sc_o;
  float invd = 1.0f / den_t;

  float4 bb0 = *(const float4*)(b1 + f0);
  float4 bb4 = *(const float4*)(b1 + f0 + 4);
  float bb[8] = {bb0.x,bb0.y,bb0.z,bb0.w,bb4.x,bb4.y,bb4.z,bb4.w};
  float hv[8];
  #pragma unroll
  for (int k = 0; k < 8; k++){
    float a_o = __shfl_xor(acc[k], 32, 64);
    float tot = acc[k] * sc + a_o * sc_o;
    float h = tot * invd + bb[k];
    hv[k] = (h > 0.f) ? h : (__expf(h) - 1.f);   // ELU
  }
  float4 l0 = *(const float4*)(W2l + f0);
  float4 l4 = *(const float4*)(W2l + f0 + 4);
  float4 r0 = *(const float4*)(W2r + f0);
  float4 r4 = *(const float4*)(W2r + f0 + 4);
  float wl[8] = {l0.x,l0.y,l0.z,l0.w,l4.x,l4.y,l4.z,l4.w};
  float wr[8] = {r0.x,r0.y,r0.z,r0.w,r4.x,r4.y,r4.z,r4.w};
  float pa = 0.f, pb = 0.f;
  #pragma unroll
  for (int k = 0; k < 8; k++){ pa += hv[k]*wl[k]; pb += hv[k]*wr[k]; }
  // reduce over 32 lanes (halves hold identical values post-merge)
  #pragma unroll
  for (int msk = 16; msk > 0; msk >>= 1){
    pa += __shfl_xor(pa, msk, 64);
    pb += __shfl_xor(pb, msk, 64);
  }
  if (lane == 0){ sl[n] = pa; sr[n] = pb; }
}

// ---------- global softmax key helpers ----------
__device__ __forceinline__ unsigned fkey(float f){
  unsigned u = __float_as_uint(f);
  return u ^ ((u >> 31) ? 0xFFFFFFFFu : 0x80000000u);
}
__device__ __forceinline__ float funkey(unsigned k){
  unsigned u = (k >> 31) ? (k ^ 0x80000000u) : ~k;
  return __uint_as_float(u);
}

// ---------- layer-2 FUSED: 16-lane group per node (16 nodes/block) ----------
__global__ __launch_bounds__(256) void k_attn2(const int* __restrict__ offsets,
                                               const float4* __restrict__ rec,
                                               const float* __restrict__ W2e,
                                               const float* __restrict__ att2,
                                               const float* __restrict__ b2p,
                                               const float* __restrict__ sl,
                                               const float* __restrict__ sr,
                                               float* __restrict__ scores,
                                               float* __restrict__ out){
  int t = threadIdx.x, l16 = t & 15;
  int n = blockIdx.x * 16 + (t >> 4);
  if (n >= N_NODESC) return;
  const float attv = att2[0];
  const float w2e0 = W2e[0], w2e1 = W2e[1], w2e2 = W2e[2];
  const float srn = sr[n];
  int beg = offsets[n], end = offsets[n + 1];
  float m = -1e30f, den = 0.f, num = 0.f;
  for (int j = beg + l16; j < end; j += 16){
    float4 rc = rec[j];
    float slv = sl[__float_as_int(rc.x)];
    float v = slv + srn + rc.y*w2e0 + rc.z*w2e1 + rc.w*w2e2;
    v = (v > 0.f) ? v : NEG_SLOPE * v;
    float lg = v * attv;
    float mn = fmaxf(m, lg);
    float corr = __expf(m - mn);
    float pe   = __expf(lg - mn);
    den = den * corr + pe;
    num = num * corr + pe * slv;
    m = mn;
  }
  float mg = g16_max(m);
  float scale = __expf(m - mg);
  float deng = g16_sum(den * scale);
  float numg = g16_sum(num * scale);
  if (l16 == 0){
    float s = numg / deng + b2p[0];
    scores[n] = s;
    out[N_NODESC + n] = s;
  }
}

// ---------- global softmax over scores (block-reduce then 1 atomic/block) ----------
__global__ __launch_bounds__(256) void k_smax_max(const float* __restrict__ scores,
                                                  unsigned* __restrict__ redmax){
  float m = -1e30f;
  for (int i = blockIdx.x * blockDim.x + threadIdx.x; i < N_NODESC;
       i += gridDim.x * blockDim.x)
    m = fmaxf(m, scores[i]);
  m = wave_max(m);
  __shared__ float ws_[4];
  int lane = threadIdx.x & 63, w = threadIdx.x >> 6;
  if (lane == 0) ws_[w] = m;
  __syncthreads();
  if (threadIdx.x == 0){
    for (int i = 1; i < 4; i++) m = fmaxf(m, ws_[i]);
    atomicMax(redmax, fkey(m));
  }
}

__global__ __launch_bounds__(256) void k_smax_sum(const float* __restrict__ scores,
                                                  const unsigned* __restrict__ redmax,
                                                  float* __restrict__ redsum){
  float mx = funkey(*redmax);
  float s = 0.f;
  for (int i = blockIdx.x * blockDim.x + threadIdx.x; i < N_NODESC;
       i += gridDim.x * blockDim.x)
    s += __expf(scores[i] - mx);
  s = wave_sum(s);
  __shared__ float ws_[4];
  int lane = threadIdx.x & 63, w = threadIdx.x >> 6;
  if (lane == 0) ws_[w] = s;
  __syncthreads();
  if (threadIdx.x == 0){
    float t = 0.f;
    for (int i = 0; i < 4; i++) t += ws_[i];
    atomicAdd(redsum, t);
  }
}

__global__ __launch_bounds__(256) void k_smax_write(const float* __restrict__ scores,
                                                    const unsigned* __restrict__ redmax,
                                                    const float* __restrict__ redsum,
                                                    float* __restrict__ out){
  int i = blockIdx.x * blockDim.x + threadIdx.x;
  if (i >= N_NODESC) return;
  float mx = funkey(*redmax);
  float inv = 1.0f / (*redsum);
  out[i] = __expf(scores[i] - mx) * inv;
}

extern "C" void kernel_launch(void* const* d_in, const int* in_sizes, int n_in,
                              void* d_out, int out_size, void* d_ws, size_t ws_size,
                              hipStream_t stream) {
  const float* x    = (const float*)d_in[0];
  const float* ea   = (const float*)d_in[1];
  const float* W1l  = (const float*)d_in[2];
  const float* W1r  = (const float*)d_in[3];
  const float* W1e  = (const float*)d_in[4];
  const float* att1 = (const float*)d_in[5];
  const float* b1   = (const float*)d_in[6];
  const float* W2l  = (const float*)d_in[7];
  const float* W2r  = (const float*)d_in[8];
  const float* W2e  = (const float*)d_in[9];
  const float* att2 = (const float*)d_in[10];
  const float* b2   = (const float*)d_in[11];
  const int*   ei   = (const int*)d_in[12];
  float* out = (float*)d_out;

  char* w = (char*)d_ws;
  size_t off = 0;
  auto alloc = [&](size_t bytes) -> char* {
    char* p = w + off;
    off = (off + bytes + 255) & ~(size_t)255;
    return p;
  };
  // ---- zero zone (memset every call) ----
  float*    meanacc = (float*)alloc(16);
  unsigned* redmax  = (unsigned*)alloc(8);
  float*    redsum  = (float*)((char*)redmax + 4);
  int*      deg     = (int*)alloc((size_t)N_NODESC * 4);
  size_t zero_bytes = off;
  // ---- rest ----
  int*   offsets = (int*)alloc((size_t)(N_NODESC + 1) * 4);
  int*   rank    = (int*)alloc((size_t)N_EDGESC * 4);
  int*   pre     = (int*)alloc((size_t)N_NODESC * 4);
  int*   bsum    = (int*)alloc((size_t)SCAN_NB * 4);
  float4* rec    = (float4*)alloc((size_t)E_TOTC * 16);
  float* sl      = (float*)alloc((size_t)N_NODESC * 4);
  float* sr      = (float*)alloc((size_t)N_NODESC * 4);
  float* scores  = (float*)alloc((size_t)N_NODESC * 4);
  _Float16* Bfrag = (_Float16*)alloc((size_t)2 * 128 * 256 * 2);
  _Float16* xl    = (_Float16*)alloc((size_t)MPAD * FDIM * 2);
  _Float16* xr    = (_Float16*)alloc((size_t)MPAD * FDIM * 2);
  (void)ws_size; (void)in_sizes; (void)n_in; (void)out_size;

  hipMemsetAsync(d_ws, 0, zero_bytes, stream);

  k_prep  <<<MEAN_NB + 256, 256, 0, stream>>>(ea, meanacc, W1l, W1r, Bfrag);
  k_count <<<(N_EDGESC + 255) / 256, 256, 0, stream>>>(ei, deg, rank);
  k_scan_pa<<<SCAN_NB, 256, 0, stream>>>(deg, pre, bsum);
  k_scan_pc<<<SCAN_NB, 256, 0, stream>>>(pre, bsum, offsets);
  k_scatter<<<(E_TOTC + 255) / 256, 256, 0, stream>>>(ei, ea, meanacc, offsets,
                                                      rank, rec);
  k_gemm_mfma<<<MPAD / 32, 256, 0, stream>>>(x, Bfrag, xl, xr);
  k_attn1 <<<N_NODESC / 4, 256, 0, stream>>>(offsets, rec, xl, xr,
                                             W1e, att1, b1, W2l, W2r, sl, sr);
  k_attn2 <<<(N_NODESC + 15) / 16, 256, 0, stream>>>(offsets, rec, W2e, att2, b2,
                                                     sl, sr, scores, out);
  k_smax_max <<<256, 256, 0, stream>>>(scores, redmax);
  k_smax_sum <<<256, 256, 0, stream>>>(scores, redmax, redsum);
  k_smax_write<<<(N_NODESC + 255) / 256, 256, 0, stream>>>(scores, redmax, redsum, out);
}

// Round 16
// 286.814 us; speedup vs baseline: 1.0649x; 1.0607x over previous
//
#include <hip/hip_runtime.h>
#include <hip/hip_bf16.h>
#include <hip/hip_fp16.h>

typedef __attribute__((ext_vector_type(8))) short short8;
typedef __attribute__((ext_vector_type(4))) float floatx4;
typedef _Float16 h2 __attribute__((ext_vector_type(2)));
typedef _Float16 h4 __attribute__((ext_vector_type(4)));
typedef _Float16 h8 __attribute__((ext_vector_type(8)));
typedef __fp16 fp16x2 __attribute__((ext_vector_type(2)));

#define N_NODESC 50000
#define MPAD     50016     // padded to 32-row tiles
#define N_EDGESC 800000
#define E_TOTC   850000    // + self loops
#define IN_DIMC  128
#define FDIM     256       // HEADS*HID
#define HEADSC   4
#define HIDC     64
#define NEG_SLOPE 0.2f
#define RESCALE_THR 8.0f

#define SCAN_TILE 1024
#define SCAN_NB   ((N_NODESC + SCAN_TILE - 1) / SCAN_TILE)   // 49
#define MEAN_NB   400
#define CVTW_NB   256
#define COUNT_NB  ((N_EDGESC + 255) / 256)                   // 3125
#define GEMM_NB   (MPAD / 32)                                // 1563

__device__ __forceinline__ float wave_sum(float v){
  #pragma unroll
  for (int m = 32; m > 0; m >>= 1) v += __shfl_xor(v, m, 64);
  return v;
}
__device__ __forceinline__ int wave_sum_i(int v){
  #pragma unroll
  for (int m = 32; m > 0; m >>= 1) v += __shfl_xor(v, m, 64);
  return v;
}
__device__ __forceinline__ float wave_max(float v){
  #pragma unroll
  for (int m = 32; m > 0; m >>= 1) v = fmaxf(v, __shfl_xor(v, m, 64));
  return v;
}
// 16-lane-group reductions (xor masks stay inside the group)
__device__ __forceinline__ float g16_sum(float v){
  #pragma unroll
  for (int m = 8; m > 0; m >>= 1) v += __shfl_xor(v, m, 64);
  return v;
}
__device__ __forceinline__ float g16_max(float v){
  #pragma unroll
  for (int m = 8; m > 0; m >>= 1) v = fmaxf(v, __shfl_xor(v, m, 64));
  return v;
}

// pack a scalar f32 into both halves of an f16 pair (v_cvt_pkrtz_f16_f32)
__device__ __forceinline__ h2 f2h2(float v){
  return __builtin_bit_cast(h2, __builtin_amdgcn_cvt_pkrtz(v, v));
}
__device__ __forceinline__ float fdot2(h2 a, h2 b, float c){
  return __builtin_amdgcn_fdot2(__builtin_bit_cast(fp16x2, a),
                                __builtin_bit_cast(fp16x2, b), c, false);
}

// ---------- fused prep: means | W cvt | degree count+rank (all independent) ----------
// blocks [0,400): edge_attr means; [400,656): W1l/W1r cvt; [656,3781): count.
// count's atomic-with-return latency overlaps the streaming mean (R16).
__global__ __launch_bounds__(256) void k_prep(const float* __restrict__ ea,
                                              float* __restrict__ meanacc,
                                              const float* __restrict__ W1l,
                                              const float* __restrict__ W1r,
                                              _Float16* __restrict__ Bfrag,
                                              const int* __restrict__ ei,
                                              int* __restrict__ deg,
                                              int* __restrict__ rank){
  int b = blockIdx.x;
  if (b < MEAN_NB){
    float s0 = 0.f, s1 = 0.f, s2 = 0.f;
    for (int i = b * 256 + threadIdx.x; i < N_EDGESC; i += MEAN_NB * 256){
      s0 += ea[i*3+0]; s1 += ea[i*3+1]; s2 += ea[i*3+2];
    }
    s0 = wave_sum(s0); s1 = wave_sum(s1); s2 = wave_sum(s2);
    __shared__ float red[3][4];
    int lane = threadIdx.x & 63, w = threadIdx.x >> 6;
    if (lane == 0){ red[0][w] = s0; red[1][w] = s1; red[2][w] = s2; }
    __syncthreads();
    if (threadIdx.x == 0){
      float t0 = 0.f, t1 = 0.f, t2 = 0.f;
      for (int i = 0; i < 4; i++){ t0 += red[0][i]; t1 += red[1][i]; t2 += red[2][i]; }
      atomicAdd(&meanacc[0], t0); atomicAdd(&meanacc[1], t1); atomicAdd(&meanacc[2], t2);
    }
  } else if (b < MEAN_NB + CVTW_NB){
    int idx = (b - MEAN_NB) * 256 + threadIdx.x;   // < 65536
    int mat = idx >> 15;
    int r   = idx & 32767;       // k*256+n
    int k   = r >> 8, n = r & 255;
    float v = mat ? W1r[r] : W1l[r];
    int pos = (mat << 15) + (((k >> 3) << 8) + n) * 8 + (k & 7);
    Bfrag[pos] = (_Float16)v;
  } else {
    int e = (b - MEAN_NB - CVTW_NB) * 256 + threadIdx.x;
    if (e < N_EDGESC)
      rank[e] = atomicAdd(&deg[ei[N_EDGESC + e]], 1);
  }
}

// ---------- fused: MFMA dual GEMM | scan phase A (independent given k_prep) ----------
// blocks [0,1563): gemm (needs Bfrag); [1563,1612): scan_pa (needs deg).
__global__ __launch_bounds__(256) void k_gemm_scan(const float* __restrict__ x,
                                                   const _Float16* __restrict__ Bfrag,
                                                   _Float16* __restrict__ xl,
                                                   _Float16* __restrict__ xr,
                                                   const int* __restrict__ deg,
                                                   int* __restrict__ pre,
                                                   int* __restrict__ bsum){
  if (blockIdx.x < GEMM_NB){
    // ---- GEMM part: one block loads 32 x-rows once, computes both mats ----
    const int r0  = blockIdx.x * 32;
    const int w = threadIdx.x >> 6, lane = threadIdx.x & 63;
    const int quad = lane >> 4, l16 = lane & 15;

    h8 afr[2][4];
    #pragma unroll
    for (int ms = 0; ms < 2; ms++){
      int row = r0 + ms*16 + l16;
      bool ok = row < N_NODESC;
      #pragma unroll
      for (int ks = 0; ks < 4; ks++){
        if (ok){
          const float* p = x + (size_t)row * IN_DIMC + ks*32 + quad*8;
          float4 v0 = *(const float4*)(p);
          float4 v1 = *(const float4*)(p + 4);
          afr[ms][ks] = h8{(_Float16)v0.x, (_Float16)v0.y, (_Float16)v0.z, (_Float16)v0.w,
                           (_Float16)v1.x, (_Float16)v1.y, (_Float16)v1.z, (_Float16)v1.w};
        } else {
          afr[ms][ks] = h8{0,0,0,0,0,0,0,0};
        }
      }
    }
    const int n0 = w * 64;
    #pragma unroll
    for (int mat = 0; mat < 2; mat++){
      const _Float16* Bm = Bfrag + ((size_t)mat << 15);
      _Float16* C = mat ? xr : xl;
      floatx4 acc[2][4];
      #pragma unroll
      for (int ms = 0; ms < 2; ms++)
        #pragma unroll
        for (int ns = 0; ns < 4; ns++){
          floatx4 z = {0.f, 0.f, 0.f, 0.f};
          acc[ms][ns] = z;
        }
      #pragma unroll
      for (int ks = 0; ks < 4; ks++){
        #pragma unroll
        for (int ns = 0; ns < 4; ns++){
          int n = n0 + ns*16 + l16;
          int kblk = ks*4 + quad;
          h8 bfr = *reinterpret_cast<const h8*>(Bm + ((size_t)kblk*256 + n)*8);
          acc[0][ns] = __builtin_amdgcn_mfma_f32_16x16x32_f16(afr[0][ks], bfr, acc[0][ns], 0, 0, 0);
          acc[1][ns] = __builtin_amdgcn_mfma_f32_16x16x32_f16(afr[1][ks], bfr, acc[1][ns], 0, 0, 0);
        }
      }
      #pragma unroll
      for (int ms = 0; ms < 2; ms++)
        #pragma unroll
        for (int ns = 0; ns < 4; ns++){
          int col = n0 + ns*16 + l16;
          #pragma unroll
          for (int rg = 0; rg < 4; rg++){
            int row = r0 + ms*16 + quad*4 + rg;
            C[(size_t)row * FDIM + col] = (_Float16)acc[ms][ns][rg];
          }
        }
    }
  } else {
    // ---- scan phase A: deg+1 per node (self-loop folded in) ----
    int b = blockIdx.x - GEMM_NB, t = threadIdx.x;
    int lane = t & 63, w = t >> 6;
    int base = b * SCAN_TILE + t * 4;
    int4 v = {0, 0, 0, 0};
    if (base + 3 < N_NODESC){
      v = *(const int4*)(deg + base);
      v.x += 1; v.y += 1; v.z += 1; v.w += 1;
    } else {
      if (base + 0 < N_NODESC) v.x = deg[base + 0] + 1;
      if (base + 1 < N_NODESC) v.y = deg[base + 1] + 1;
      if (base + 2 < N_NODESC) v.z = deg[base + 2] + 1;
      if (base + 3 < N_NODESC) v.w = deg[base + 3] + 1;
    }
    int s = v.x + v.y + v.z + v.w;
    int inc = s;
    #pragma unroll
    for (int off = 1; off < 64; off <<= 1){
      int u = __shfl_up(inc, off, 64);
      if (lane >= off) inc += u;
    }
    __shared__ int wsum[4];
    if (lane == 63) wsum[w] = inc;
    __syncthreads();
    int wadd = 0;
    #pragma unroll
    for (int i = 0; i < 4; i++) if (i < w) wadd += wsum[i];
    int excl = inc - s + wadd;
    if (base + 3 < N_NODESC){
      int4 o;
      o.x = excl; o.y = o.x + v.x; o.z = o.y + v.y; o.w = o.z + v.z;
      *(int4*)(pre + base) = o;
    } else {
      int run = excl;
      if (base + 0 < N_NODESC){ pre[base + 0] = run; run += v.x; }
      if (base + 1 < N_NODESC){ pre[base + 1] = run; run += v.y; }
      if (base + 2 < N_NODESC){ pre[base + 2] = run; run += v.z; }
      if (base + 3 < N_NODESC){ pre[base + 3] = run; }
    }
    if (t == 255) bsum[b] = wsum[0] + wsum[1] + wsum[2] + wsum[3];
  }
}

// phase C: each block redundantly reduces the 49 block sums in one wave to
// get its own prefix; block 0 writes the grand total.
__global__ __launch_bounds__(256) void k_scan_pc(const int* __restrict__ pre,
                                                 const int* __restrict__ bsum,
                                                 int* __restrict__ offsets){
  int b = blockIdx.x;
  __shared__ int sadd;
  if (threadIdx.x < 64){
    int lane = threadIdx.x;
    int v   = (lane < SCAN_NB) ? bsum[lane] : 0;
    int pfx = (lane < b) ? v : 0;
    pfx = wave_sum_i(pfx);
    if (lane == 0) sadd = pfx;
    if (b == 0){
      int tot = wave_sum_i(v);
      if (lane == 0) offsets[N_NODESC] = tot;
    }
  }
  __syncthreads();
  int add = sadd;
  int base = b * SCAN_TILE + threadIdx.x * 4;
  if (base + 3 < N_NODESC){
    int4 p = *(const int4*)(pre + base);
    p.x += add; p.y += add; p.z += add; p.w += add;
    *(int4*)(offsets + base) = p;
  } else {
    #pragma unroll
    for (int f = 0; f < 4; f++){
      int i = base + f;
      if (i < N_NODESC) offsets[i] = pre[i] + add;
    }
  }
}

// packed edge record: .x = src (int bits), .y/.z/.w = edge_attr (f32).
// position = offsets[dst] + rank[e] (no atomics); self-loop of node i
// deterministically owns slot offsets[i+1]-1 (reserved by +1 in scan).
__global__ __launch_bounds__(256) void k_scatter(const int* __restrict__ ei,
                                                 const float* __restrict__ ea,
                                                 const float* __restrict__ meanacc,
                                                 const int* __restrict__ offsets,
                                                 const int* __restrict__ rank,
                                                 float4* __restrict__ rec){
  int e = blockIdx.x * blockDim.x + threadIdx.x;
  if (e >= E_TOTC) return;
  int pos; float4 r;
  if (e < N_EDGESC){
    int src = ei[e], dst = ei[N_EDGESC + e];
    r.x = __int_as_float(src);
    r.y = ea[e*3+0]; r.z = ea[e*3+1]; r.w = ea[e*3+2];
    pos = offsets[dst] + rank[e];
  } else {
    int i = e - N_EDGESC;
    const float inv = 1.0f / (float)N_EDGESC;
    r.x = __int_as_float(i);
    r.y = meanacc[0]*inv; r.z = meanacc[1]*inv; r.w = meanacc[2]*inv;
    pos = offsets[i + 1] - 1;      // reserved last slot
  }
  rec[pos] = r;
}

// ---------- layer-1 FUSED: one wave per node, 2 edges/iteration ----------
// [R11/R13/R15-verified: 89.2-89.9 us, VALUBusy 83%, VGPR 40. 4-edge
//  regressed; h2-prepack regressed; (256,8) spilled (cap 32).]
// (256,6): cap 256/6=42 >= 40 needed -> no spill, 6 waves/SIMD (R16 test;
// occupancy was pinned at 4/SIMD by the (256,4) minimum, not by VGPR).
__global__ __launch_bounds__(256, 6) void k_attn1(const int* __restrict__ offsets,
                                                  const float4* __restrict__ rec,
                                                  const _Float16* __restrict__ xl,
                                                  const _Float16* __restrict__ xr,
                                                  const float* __restrict__ W1e,
                                                  const float* __restrict__ att1,
                                                  const float* __restrict__ b1,
                                                  const float* __restrict__ W2l,
                                                  const float* __restrict__ W2r,
                                                  float* __restrict__ sl,
                                                  float* __restrict__ sr){
  const int t = threadIdx.x, lane = t & 63, w = t >> 6;
  const int n = blockIdx.x * 4 + w;
  const int half = lane >> 5, l32 = lane & 31;
  const int f0 = l32 * 8;

  // per-wave invariants: 8 features/lane as f16 pairs
  h2 xrp[4], w0p[4], w1p[4], w2p[4], atp[4];
  {
    h8 xw = *(const h8*)(xr + (size_t)n * FDIM + f0);
    #pragma unroll
    for (int k = 0; k < 4; k++) xrp[k] = h2{xw[2*k], xw[2*k+1]};
    float4 a0 = *(const float4*)(W1e + f0);
    float4 a1 = *(const float4*)(W1e + f0 + 4);
    w0p[0]=h2{(_Float16)a0.x,(_Float16)a0.y}; w0p[1]=h2{(_Float16)a0.z,(_Float16)a0.w};
    w0p[2]=h2{(_Float16)a1.x,(_Float16)a1.y}; w0p[3]=h2{(_Float16)a1.z,(_Float16)a1.w};
    float4 b0 = *(const float4*)(W1e + FDIM + f0);
    float4 b4 = *(const float4*)(W1e + FDIM + f0 + 4);
    w1p[0]=h2{(_Float16)b0.x,(_Float16)b0.y}; w1p[1]=h2{(_Float16)b0.z,(_Float16)b0.w};
    w1p[2]=h2{(_Float16)b4.x,(_Float16)b4.y}; w1p[3]=h2{(_Float16)b4.z,(_Float16)b4.w};
    float4 c0 = *(const float4*)(W1e + 2*FDIM + f0);
    float4 c4 = *(const float4*)(W1e + 2*FDIM + f0 + 4);
    w2p[0]=h2{(_Float16)c0.x,(_Float16)c0.y}; w2p[1]=h2{(_Float16)c0.z,(_Float16)c0.w};
    w2p[2]=h2{(_Float16)c4.x,(_Float16)c4.y}; w2p[3]=h2{(_Float16)c4.z,(_Float16)c4.w};
    float4 d0 = *(const float4*)(att1 + f0);
    float4 d4 = *(const float4*)(att1 + f0 + 4);
    atp[0]=h2{(_Float16)d0.x,(_Float16)d0.y}; atp[1]=h2{(_Float16)d0.z,(_Float16)d0.w};
    atp[2]=h2{(_Float16)d4.x,(_Float16)d4.y}; atp[3]=h2{(_Float16)d4.z,(_Float16)d4.w};
  }
  const h2 nsl2 = h2{(_Float16)NEG_SLOPE, (_Float16)NEG_SLOPE};
  const int beg = offsets[n], end = offsets[n + 1];
  const int last = end - 1;

  float m = -1e30f, den = 0.f;
  float acc[8] = {0.f,0.f,0.f,0.f,0.f,0.f,0.f,0.f};

  // pipeline prologue (this half's edge stream: beg+half, step 2)
  int j = beg + half;
  float4 rc  = rec[min(j, last)];
  float4 rcn = rec[min(j + 2, last)];
  unsigned off0 = ((unsigned)__float_as_int(rc.x) << 8) + f0;  // elements, fits 32b
  h8 raw = *(const h8*)(xl + off0);

  for (; j < end; j += 2){
    // issue next gather + record 2 ahead
    unsigned offn = ((unsigned)__float_as_int(rcn.x) << 8) + f0;
    h8 rawn = *(const h8*)(xl + offn);
    const float e0 = rc.y, e1 = rc.z, e2 = rc.w;
    rc = rcn;
    rcn = rec[min(j + 4, last)];

    h2 he0 = f2h2(e0), he1 = f2h2(e1), he2 = f2h2(e2);
    float pp = 0.f;
    #pragma unroll
    for (int k = 0; k < 4; k++){
      h2 xk = h2{raw[2*k], raw[2*k+1]};
      h2 v = xk + xrp[k] + he0*w0p[k] + he1*w1p[k] + he2*w2p[k];
      v = __builtin_elementwise_max(v, nsl2 * v);
      pp = fdot2(v, atp[k], pp);
    }
    // 8-lane (per-head, per-half) reduce
    pp += __shfl_xor(pp, 1, 64);
    pp += __shfl_xor(pp, 2, 64);
    pp += __shfl_xor(pp, 4, 64);

    // deferred-max online softmax (per half)
    if (pp > m + RESCALE_THR){
      float corr = __expf(m - pp);
      den *= corr;
      #pragma unroll
      for (int k = 0; k < 8; k++) acc[k] *= corr;
      m = pp;
    }
    float al = __expf(pp - m);
    den += al;
    #pragma unroll
    for (int k = 0; k < 8; k++) acc[k] = fmaf((float)raw[k], al, acc[k]);

    raw = rawn;
  }

  // exact merge of the two halves' softmax states
  float m_o   = __shfl_xor(m, 32, 64);
  float den_o = __shfl_xor(den, 32, 64);
  float m_t = fmaxf(m, m_o);
  float sc   = __expf(m - m_t);
  float sc_o = __expf(m_o - m_t);
  float den_t = den * sc + den_o * sc_o;
  float invd = 1.0f / den_t;

  float4 bb0 = *(const float4*)(b1 + f0);
  float4 bb4 = *(const float4*)(b1 + f0 + 4);
  float bb[8] = {bb0.x,bb0.y,bb0.z,bb0.w,bb4.x,bb4.y,bb4.z,bb4.w};
  float hv[8];
  #pragma unroll
  for (int k = 0; k < 8; k++){
    float a_o = __shfl_xor(acc[k], 32, 64);
    float tot = acc[k] * sc + a_o * sc_o;
    float h = tot * invd + bb[k];
    hv[k] = (h > 0.f) ? h : (__expf(h) - 1.f);   // ELU
  }
  float4 l0 = *(const float4*)(W2l + f0);
  float4 l4 = *(const float4*)(W2l + f0 + 4);
  float4 r0 = *(const float4*)(W2r + f0);
  float4 r4 = *(const float4*)(W2r + f0 + 4);
  float wl[8] = {l0.x,l0.y,l0.z,l0.w,l4.x,l4.y,l4.z,l4.w};
  float wr[8] = {r0.x,r0.y,r0.z,r0.w,r4.x,r4.y,r4.z,r4.w};
  float pa = 0.f, pb = 0.f;
  #pragma unroll
  for (int k = 0; k < 8; k++){ pa += hv[k]*wl[k]; pb += hv[k]*wr[k]; }
  // reduce over 32 lanes (halves hold identical values post-merge)
  #pragma unroll
  for (int msk = 16; msk > 0; msk >>= 1){
    pa += __shfl_xor(pa, msk, 64);
    pb += __shfl_xor(pb, msk, 64);
  }
  if (lane == 0){ sl[n] = pa; sr[n] = pb; }
}

// ---------- global softmax key helpers ----------
__device__ __forceinline__ unsigned fkey(float f){
  unsigned u = __float_as_uint(f);
  return u ^ ((u >> 31) ? 0xFFFFFFFFu : 0x80000000u);
}
__device__ __forceinline__ float funkey(unsigned k){
  unsigned u = (k >> 31) ? (k ^ 0x80000000u) : ~k;
  return __uint_as_float(u);
}

// ---------- layer-2 FUSED: 16-lane group per node (16 nodes/block) ----------
__global__ __launch_bounds__(256) void k_attn2(const int* __restrict__ offsets,
                                               const float4* __restrict__ rec,
                                               const float* __restrict__ W2e,
                                               const float* __restrict__ att2,
                                               const float* __restrict__ b2p,
                                               const float* __restrict__ sl,
                                               const float* __restrict__ sr,
                                               float* __restrict__ scores,
                                               float* __restrict__ out){
  int t = threadIdx.x, l16 = t & 15;
  int n = blockIdx.x * 16 + (t >> 4);
  if (n >= N_NODESC) return;
  const float attv = att2[0];
  const float w2e0 = W2e[0], w2e1 = W2e[1], w2e2 = W2e[2];
  const float srn = sr[n];
  int beg = offsets[n], end = offsets[n + 1];
  float m = -1e30f, den = 0.f, num = 0.f;
  for (int j = beg + l16; j < end; j += 16){
    float4 rc = rec[j];
    float slv = sl[__float_as_int(rc.x)];
    float v = slv + srn + rc.y*w2e0 + rc.z*w2e1 + rc.w*w2e2;
    v = (v > 0.f) ? v : NEG_SLOPE * v;
    float lg = v * attv;
    float mn = fmaxf(m, lg);
    float corr = __expf(m - mn);
    float pe   = __expf(lg - mn);
    den = den * corr + pe;
    num = num * corr + pe * slv;
    m = mn;
  }
  float mg = g16_max(m);
  float scale = __expf(m - mg);
  float deng = g16_sum(den * scale);
  float numg = g16_sum(num * scale);
  if (l16 == 0){
    float s = numg / deng + b2p[0];
    scores[n] = s;
    out[N_NODESC + n] = s;
  }
}

// ---------- global softmax over scores (block-reduce then 1 atomic/block) ----------
__global__ __launch_bounds__(256) void k_smax_max(const float* __restrict__ scores,
                                                  unsigned* __restrict__ redmax){
  float m = -1e30f;
  for (int i = blockIdx.x * blockDim.x + threadIdx.x; i < N_NODESC;
       i += gridDim.x * blockDim.x)
    m = fmaxf(m, scores[i]);
  m = wave_max(m);
  __shared__ float ws_[4];
  int lane = threadIdx.x & 63, w = threadIdx.x >> 6;
  if (lane == 0) ws_[w] = m;
  __syncthreads();
  if (threadIdx.x == 0){
    for (int i = 1; i < 4; i++) m = fmaxf(m, ws_[i]);
    atomicMax(redmax, fkey(m));
  }
}

__global__ __launch_bounds__(256) void k_smax_sum(const float* __restrict__ scores,
                                                  const unsigned* __restrict__ redmax,
                                                  float* __restrict__ redsum){
  float mx = funkey(*redmax);
  float s = 0.f;
  for (int i = blockIdx.x * blockDim.x + threadIdx.x; i < N_NODESC;
       i += gridDim.x * blockDim.x)
    s += __expf(scores[i] - mx);
  s = wave_sum(s);
  __shared__ float ws_[4];
  int lane = threadIdx.x & 63, w = threadIdx.x >> 6;
  if (lane == 0) ws_[w] = s;
  __syncthreads();
  if (threadIdx.x == 0){
    float t = 0.f;
    for (int i = 0; i < 4; i++) t += ws_[i];
    atomicAdd(redsum, t);
  }
}

__global__ __launch_bounds__(256) void k_smax_write(const float* __restrict__ scores,
                                                    const unsigned* __restrict__ redmax,
                                                    const float* __restrict__ redsum,
                                                    float* __restrict__ out){
  int i = blockIdx.x * blockDim.x + threadIdx.x;
  if (i >= N_NODESC) return;
  float mx = funkey(*redmax);
  float inv = 1.0f / (*redsum);
  out[i] = __expf(scores[i] - mx) * inv;
}

extern "C" void kernel_launch(void* const* d_in, const int* in_sizes, int n_in,
                              void* d_out, int out_size, void* d_ws, size_t ws_size,
                              hipStream_t stream) {
  const float* x    = (const float*)d_in[0];
  const float* ea   = (const float*)d_in[1];
  const float* W1l  = (const float*)d_in[2];
  const float* W1r  = (const float*)d_in[3];
  const float* W1e  = (const float*)d_in[4];
  const float* att1 = (const float*)d_in[5];
  const float* b1   = (const float*)d_in[6];
  const float* W2l  = (const float*)d_in[7];
  const float* W2r  = (const float*)d_in[8];
  const float* W2e  = (const float*)d_in[9];
  const float* att2 = (const float*)d_in[10];
  const float* b2   = (const float*)d_in[11];
  const int*   ei   = (const int*)d_in[12];
  float* out = (float*)d_out;

  char* w = (char*)d_ws;
  size_t off = 0;
  auto alloc = [&](size_t bytes) -> char* {
    char* p = w + off;
    off = (off + bytes + 255) & ~(size_t)255;
    return p;
  };
  // ---- zero zone (memset every call) ----
  float*    meanacc = (float*)alloc(16);
  unsigned* redmax  = (unsigned*)alloc(8);
  float*    redsum  = (float*)((char*)redmax + 4);
  int*      deg     = (int*)alloc((size_t)N_NODESC * 4);
  size_t zero_bytes = off;
  // ---- rest ----
  int*   offsets = (int*)alloc((size_t)(N_NODESC + 1) * 4);
  int*   rank    = (int*)alloc((size_t)N_EDGESC * 4);
  int*   pre     = (int*)alloc((size_t)N_NODESC * 4);
  int*   bsum    = (int*)alloc((size_t)SCAN_NB * 4);
  float4* rec    = (float4*)alloc((size_t)E_TOTC * 16);
  float* sl      = (float*)alloc((size_t)N_NODESC * 4);
  float* sr      = (float*)alloc((size_t)N_NODESC * 4);
  float* scores  = (float*)alloc((size_t)N_NODESC * 4);
  _Float16* Bfrag = (_Float16*)alloc((size_t)2 * 128 * 256 * 2);
  _Float16* xl    = (_Float16*)alloc((size_t)MPAD * FDIM * 2);
  _Float16* xr    = (_Float16*)alloc((size_t)MPAD * FDIM * 2);
  (void)ws_size; (void)in_sizes; (void)n_in; (void)out_size;

  hipMemsetAsync(d_ws, 0, zero_bytes, stream);

  k_prep     <<<MEAN_NB + CVTW_NB + COUNT_NB, 256, 0, stream>>>(ea, meanacc,
                                               W1l, W1r, Bfrag, ei, deg, rank);
  k_gemm_scan<<<GEMM_NB + SCAN_NB, 256, 0, stream>>>(x, Bfrag, xl, xr,
                                                     deg, pre, bsum);
  k_scan_pc  <<<SCAN_NB, 256, 0, stream>>>(pre, bsum, offsets);
  k_scatter  <<<(E_TOTC + 255) / 256, 256, 0, stream>>>(ei, ea, meanacc, offsets,
                                                        rank, rec);
  k_attn1    <<<N_NODESC / 4, 256, 0, stream>>>(offsets, rec, xl, xr,
                                                W1e, att1, b1, W2l, W2r, sl, sr);
  k_attn2    <<<(N_NODESC + 15) / 16, 256, 0, stream>>>(offsets, rec, W2e, att2, b2,
                                                        sl, sr, scores, out);
  k_smax_max <<<256, 256, 0, stream>>>(scores, redmax);
  k_smax_sum <<<256, 256, 0, stream>>>(scores, redmax, redsum);
  k_smax_write<<<(N_NODESC + 255) / 256, 256, 0, stream>>>(scores, redmax, redsum, out);
}